// Round 11
// baseline (115.971 us; speedup 1.0000x reference)
//
#include <hip/hip_runtime.h>

#define TILE_X 32
#define TILE_Y 16
#define NSLOT 1024
#define VST 41   // odd stride: lane->bank (9r+2c) mod 32 -> exactly 2 lanes/bank

__device__ __forceinline__ float4 f4_sm(float4 a, float4 b, float4 c) {  // a + 2b + c
    return make_float4(fmaf(2.f, b.x, a.x) + c.x, fmaf(2.f, b.y, a.y) + c.y,
                       fmaf(2.f, b.z, a.z) + c.z, fmaf(2.f, b.w, a.w) + c.w);
}
__device__ __forceinline__ float4 f4_sub(float4 a, float4 b) {
    return make_float4(a.x - b.x, a.y - b.y, a.z - b.z, a.w - b.w);
}
__device__ __forceinline__ float4 f4_add(float4 a, float4 b) {
    return make_float4(a.x + b.x, a.y + b.y, a.z + b.z, a.w + b.w);
}

__global__ __launch_bounds__(256, 8) void nms_loss_kernel(
    const float* __restrict__ tl, const float* __restrict__ pl,
    double* __restrict__ acc_d, float* __restrict__ acc_f,
    int H, int W)
{
    // V fields: rows = output rows 0..15, col u <-> gx = x0+u-4 (u=0..39 used)
    __shared__ float V1_s[TILE_Y * VST];
    __shared__ float V2_s[TILE_Y * VST];
    __shared__ float V3_s[TILE_Y * VST];
    __shared__ float e_s[(TILE_Y + 2) * VST];  // row v <-> gy = y0+v-1

    const int ch = blockIdx.z;
    const int y0 = blockIdx.y * TILE_Y, x0 = blockIdx.x * TILE_X;
    const float* tc = tl + (size_t)ch * H * W;
    const float* pc = pl + (size_t)ch * H * W;
    const int tid = threadIdx.x;
    const int wid = tid >> 6, lane = tid & 63;
    const int r  = tid >> 4;             // output row 0..15
    const int cp = (tid & 15) << 1;      // output col base 0,2,..,30
    const int y  = y0 + r;
    const bool xint = (x0 != 0) && (x0 != W - TILE_X);

    // ===== stage: V groups [0,160), e groups [0,180); each thread <=2 groups =====
    if (xint) {
        // ---- first assignment: tid<160 -> V group tid; tid in [160,256) -> e group tid-160
        if (tid < 160) {
            int v = tid / 10, c4 = (tid - v * 10) * 4;
            int yv = y0 + v;
            const float* bp = tc + (x0 - 4 + c4);
            float4 V1, V2, V3;
            if (yv >= 2 && yv <= H - 3) {
                float4 A  = *(const float4*)(bp + (yv - 2) * W);
                float4 Bq = *(const float4*)(bp + (yv - 1) * W);
                float4 Cq = *(const float4*)(bp + yv * W);
                float4 E  = *(const float4*)(bp + (yv + 1) * W);
                float4 G  = *(const float4*)(bp + (yv + 2) * W);
                float4 s04 = f4_add(A, G), s13 = f4_add(Bq, E);
                float4 d40 = f4_sub(G, A), d31 = f4_sub(E, Bq);
                V1 = make_float4(fmaf(6.f, Cq.x, fmaf(4.f, s13.x, s04.x)),
                                 fmaf(6.f, Cq.y, fmaf(4.f, s13.y, s04.y)),
                                 fmaf(6.f, Cq.z, fmaf(4.f, s13.z, s04.z)),
                                 fmaf(6.f, Cq.w, fmaf(4.f, s13.w, s04.w)));
                V3 = make_float4(fmaf(-2.f, Cq.x, s04.x), fmaf(-2.f, Cq.y, s04.y),
                                 fmaf(-2.f, Cq.z, s04.z), fmaf(-2.f, Cq.w, s04.w));
                V2 = make_float4(fmaf(2.f, d31.x, d40.x), fmaf(2.f, d31.y, d40.y),
                                 fmaf(2.f, d31.z, d40.z), fmaf(2.f, d31.w, d40.w));
            } else {
                int um = max(yv - 1, 0), up = min(yv + 1, H - 1);
                int ia = max(um - 1, 0), ig = min(up + 1, H - 1);
                float4 A  = *(const float4*)(bp + ia * W);
                float4 Bq = *(const float4*)(bp + um * W);
                float4 Cq = *(const float4*)(bp + (um + 1) * W);
                float4 Dq = *(const float4*)(bp + yv * W);
                float4 E  = *(const float4*)(bp + up * W);
                float4 F  = *(const float4*)(bp + (up - 1) * W);
                float4 G  = *(const float4*)(bp + ig * W);
                float4 Bm = f4_sm(A, Bq, Cq), Bc = f4_sm(Bq, Dq, E), Bp_ = f4_sm(F, E, G);
                float4 Dm = f4_sub(Cq, A),   Dc = f4_sub(E, Bq),    Dp  = f4_sub(G, F);
                V1 = f4_sm(Bm, Bc, Bp_); V2 = f4_sm(Dm, Dc, Dp); V3 = f4_sub(Dp, Dm);
            }
            float* d1 = &V1_s[v * VST + c4];
            float* d2 = &V2_s[v * VST + c4];
            float* d3 = &V3_s[v * VST + c4];
            d1[0] = V1.x; d1[1] = V1.y; d1[2] = V1.z; d1[3] = V1.w;
            d2[0] = V2.x; d2[1] = V2.y; d2[2] = V2.z; d2[3] = V2.w;
            d3[0] = V3.x; d3[1] = V3.y; d3[2] = V3.z; d3[3] = V3.w;
        } else {
            int g = tid - 160;                    // e groups 0..95
            int v = g / 10, c4 = (g - v * 10) * 4;
            int gy = y0 + v - 1; gy = gy < 0 ? -gy : (gy >= H ? 2 * H - 2 - gy : gy);
            float4 p = *(const float4*)(pc + gy * W + (x0 - 4 + c4));
            float* d = &e_s[v * VST + c4];
            d[0] = __expf(0.1f * p.x); d[1] = __expf(0.1f * p.y);
            d[2] = __expf(0.1f * p.z); d[3] = __expf(0.1f * p.w);
        }
        // ---- second assignment: tid<84 -> e group 96+tid
        if (tid < 84) {
            int g = 96 + tid;
            int v = g / 10, c4 = (g - v * 10) * 4;
            int gy = y0 + v - 1; gy = gy < 0 ? -gy : (gy >= H ? 2 * H - 2 - gy : gy);
            float4 p = *(const float4*)(pc + gy * W + (x0 - 4 + c4));
            float* d = &e_s[v * VST + c4];
            d[0] = __expf(0.1f * p.x); d[1] = __expf(0.1f * p.y);
            d[2] = __expf(0.1f * p.z); d[3] = __expf(0.1f * p.w);
        }
    } else {
        // x-border: scalar, clamped cols (verified R8/R9 path; row counts only change)
        for (int i = tid; i < TILE_Y * 40; i += 256) {
            int v = i / 40, u = i - v * 40;
            int yv = y0 + v;
            int gx = min(max(x0 + u - 4, 0), W - 1);
            const float* bp = tc + gx;
            int um = max(yv - 1, 0), up = min(yv + 1, H - 1);
            int ia = max(um - 1, 0), ig = min(up + 1, H - 1);
            float A = bp[ia * W], Bq = bp[um * W], Cq = bp[(um + 1) * W];
            float Dq = bp[yv * W], E = bp[up * W], F = bp[(up - 1) * W], G = bp[ig * W];
            float Bm = fmaf(2.f, Bq, A) + Cq, Bc = fmaf(2.f, Dq, Bq) + E, Bp_ = fmaf(2.f, E, F) + G;
            float Dm = Cq - A, Dc = E - Bq, Dp = G - F;
            V1_s[v * VST + u] = fmaf(2.f, Bc, Bm) + Bp_;
            V2_s[v * VST + u] = fmaf(2.f, Dc, Dm) + Dp;
            V3_s[v * VST + u] = Dp - Dm;
        }
        for (int i = tid; i < (TILE_Y + 2) * 40; i += 256) {
            int v = i / 40, u = i - v * 40;
            int gy = y0 + v - 1; gy = gy < 0 ? -gy : (gy >= H ? 2 * H - 2 - gy : gy);
            int gx = x0 + u - 4; gx = gx < 0 ? -gx : (gx >= W ? 2 * W - 2 - gx : gx);
            e_s[v * VST + u] = __expf(0.1f * pc[gy * W + gx]);
        }
    }

    // mask load issued before the barrier: latency hides under the sync
    const float2 maskv = *(const float2*)(tc + (size_t)y * W + x0 + cp);
    __syncthreads();

    // ===== compute: H-pass + tail, 2 px/thread =====
    float V1[6], V2[6], V3[6];
    {
        const int rb = r * VST + cp + 2;   // u = cp+2+jj <-> gx = x0+cp-2+jj
        #pragma unroll
        for (int jj = 0; jj < 6; ++jj) {
            V1[jj] = V1_s[rb + jj];
            V2[jj] = V2_s[rb + jj];
            V3[jj] = V3_s[rb + jj];
        }
    }

    float xx2[2], xy2[2], yy2[2];
    #pragma unroll
    for (int j = 0; j < 2; ++j) {
        int x = x0 + cp + j;
        float xx, xy, yy;
        if (xint || (x >= 2 && x <= W - 3)) {
            xx = (V1[j] + V1[j + 4]) - 2.f * V1[j + 2];
            xy = (V2[j + 4] - V2[j]) + 2.f * (V2[j + 3] - V2[j + 1]);
            yy = (V3[j] + V3[j + 4]) + 4.f * (V3[j + 1] + V3[j + 3]) + 6.f * V3[j + 2];
        } else {
            float hdd[5], hds[5], hss[5];
            if (x == 0) {
                hdd[0]=0; hdd[1]=0;  hdd[2]=0;  hdd[3]=-1; hdd[4]=1;
                hds[0]=0; hds[1]=0;  hds[2]=-2; hds[3]=1;  hds[4]=1;
                hss[0]=0; hss[1]=0;  hss[2]=10; hss[3]=5;  hss[4]=1;
            } else if (x == 1) {
                hdd[0]=0; hdd[1]=1;  hdd[2]=-2; hdd[3]=0;  hdd[4]=1;
                hds[0]=0; hds[1]=-3; hds[2]=0;  hds[3]=2;  hds[4]=1;
                hss[0]=0; hss[1]=5;  hss[2]=6;  hss[3]=4;  hss[4]=1;
            } else if (x == W - 1) {
                hdd[0]=1; hdd[1]=-1; hdd[2]=0;  hdd[3]=0;  hdd[4]=0;
                hds[0]=-1;hds[1]=-1; hds[2]=2;  hds[3]=0;  hds[4]=0;
                hss[0]=1; hss[1]=5;  hss[2]=10; hss[3]=0;  hss[4]=0;
            } else { // x == W-2
                hdd[0]=1; hdd[1]=0;  hdd[2]=-2; hdd[3]=1;  hdd[4]=0;
                hds[0]=-1;hds[1]=-2; hds[2]=0;  hds[3]=3;  hds[4]=0;
                hss[0]=1; hss[1]=4;  hss[2]=6;  hss[3]=5;  hss[4]=0;
            }
            xx = 0.f; xy = 0.f; yy = 0.f;
            #pragma unroll
            for (int m = 0; m < 5; ++m) {
                xx = fmaf(hdd[m], V1[j + m], xx);
                xy = fmaf(hds[m], V2[j + m], xy);
                yy = fmaf(hss[m], V3[j + m], yy);
            }
        }
        xx2[j] = xx; xy2[j] = xy; yy2[j] = yy;
    }

    float m2[2] = {maskv.x, maskv.y};

    // e window 3x4: rows y-1..y+1 (e_s rows r..r+2), cols gx = x-1..x+2
    float e0[4], e1[4], e2[4];
    {
        const float* eb = &e_s[r * VST + cp + 3];
        #pragma unroll
        for (int m = 0; m < 4; ++m) {
            e0[m] = eb[m];
            e1[m] = eb[VST + m];
            e2[m] = eb[2 * VST + m];
        }
    }

    float partial = 0.f;
    #pragma unroll
    for (int j = 0; j < 2; ++j) {
        if (m2[j] > 0.f) {
            const int m = j + 1;
            float xx = xx2[j], xy = xy2[j], yy = yy2[j];   // 64x scaled
            float den = xx + 6.4e-6f;                       // 64*(grad_xx+1e-7)
            float sa  = 6.4e-6f - xy;                       // 64*(1e-7-grad_xy)
            float ax = fabsf(den), ay = fabsf(yy);
            bool isH = ay < 0.41421356f * ax;    // tan(22.5), mul-compare
            bool isV = ay >= 2.41421356f * ax;   // tan(67.5)
            bool qp  = ((yy * sa) * den) > 0.f;  // sign of q
            float ec = e1[m];
            float n1 = isH ? e1[m + 1] : (isV ? e2[m] : (qp ? e2[m - 1] : e2[m + 1]));
            float n2 = isH ? e1[m - 1] : (isV ? e0[m] : (qp ? e0[m + 1] : e0[m - 1]));
            partial += __logf(__fdividef(ec, ec + n1 + n2 + 1e-7f));
        }
    }

    // ---- wave reduction + spread atomics ----
    for (int off = 32; off > 0; off >>= 1)
        partial += __shfl_down(partial, off, 64);
    if (lane == 0) {
        int fid = (blockIdx.z * gridDim.y + blockIdx.y) * gridDim.x + blockIdx.x;
        if (acc_d) atomicAdd(&acc_d[(fid * 4 + wid) & (NSLOT - 1)], (double)partial);
        else       atomicAdd(acc_f, partial);
    }
}

__global__ void finalize_kernel(const double* acc_d, float* out,
                                int use_double, float inv_b)
{
    if (use_double) {
        int l = threadIdx.x;
        double s = 0.0;
        for (int i = l; i < NSLOT; i += 64) s += acc_d[i];
        for (int off = 32; off > 0; off >>= 1) s += __shfl_down(s, off, 64);
        if (l == 0) out[0] = (float)(-s * (double)inv_b);
    } else {
        if (threadIdx.x == 0) out[0] = -out[0] * inv_b;
    }
}

extern "C" void kernel_launch(void* const* d_in, const int* in_sizes, int n_in,
                              void* d_out, int out_size, void* d_ws, size_t ws_size,
                              hipStream_t stream)
{
    const float* tl = (const float*)d_in[0];
    const float* pl = (const float*)d_in[1];
    float* out = (float*)d_out;

    const int H = 512, W = 512, B = 4;

    double* acc_d = nullptr;
    float* acc_f = nullptr;
    int use_double = 0;
    if (ws_size >= NSLOT * sizeof(double)) {
        acc_d = (double*)d_ws;
        use_double = 1;
        hipMemsetAsync(acc_d, 0, NSLOT * sizeof(double), stream);
    } else {
        acc_f = out;
        hipMemsetAsync(out, 0, sizeof(float), stream);
    }

    dim3 grid(W / TILE_X, H / TILE_Y, 76);
    nms_loss_kernel<<<grid, 256, 0, stream>>>(tl, pl, acc_d, acc_f, H, W);
    finalize_kernel<<<1, 64, 0, stream>>>(acc_d, out, use_double, 1.0f / (float)B);
}

// Round 12
// 112.146 us; speedup vs baseline: 1.0341x; 1.0341x over previous
//
#include <hip/hip_runtime.h>

#define TILE 32
#define NSLOT 1024
#define VST 41   // odd stride: (9r+4c) mod 32 -> exactly 2 lanes/bank (free)

__device__ __forceinline__ float4 f4_sm(float4 a, float4 b, float4 c) {  // a + 2b + c
    return make_float4(fmaf(2.f, b.x, a.x) + c.x, fmaf(2.f, b.y, a.y) + c.y,
                       fmaf(2.f, b.z, a.z) + c.z, fmaf(2.f, b.w, a.w) + c.w);
}
__device__ __forceinline__ float4 f4_sub(float4 a, float4 b) {
    return make_float4(a.x - b.x, a.y - b.y, a.z - b.z, a.w - b.w);
}
__device__ __forceinline__ float4 f4_add(float4 a, float4 b) {
    return make_float4(a.x + b.x, a.y + b.y, a.z + b.z, a.w + b.w);
}

__global__ __launch_bounds__(256, 7) void nms_loss_kernel(
    const float* __restrict__ tl, const float* __restrict__ pl,
    double* __restrict__ acc_d, float* __restrict__ acc_f,
    int H, int W)
{
    // Wave-autonomous: wave wid owns output rows 8*wid..8*wid+7.
    // V rows are wave-disjoint; e rows 8*wid..8*wid+9 overlap neighbors but each
    // wave writes every row it reads (duplicate writes carry identical values).
    __shared__ float V1_s[32 * VST];
    __shared__ float V2_s[32 * VST];
    __shared__ float V3_s[32 * VST];
    __shared__ float e_s[34 * VST];   // row v <-> gy = y0+v-1, col u <-> gx = x0+u-4

    const int ch = blockIdx.z;
    const int y0 = blockIdx.y * TILE, x0 = blockIdx.x * TILE;
    const float* tc = tl + (size_t)ch * H * W;
    const float* pc = pl + (size_t)ch * H * W;
    const int tid = threadIdx.x;
    const int wid = tid >> 6, lane = tid & 63;
    const int r  = (wid << 3) + (lane >> 3);   // output row 0..31 (wave-local 8)
    const int cs = (lane & 7) << 2;            // output col base 0,4,..,28
    const int y  = y0 + r;
    const bool xint = (x0 != 0) && (x0 != W - TILE);

    // mask load issued first: HBM latency hides under staging
    const float4 maskv = *(const float4*)(tc + (size_t)y * W + x0 + cs);

    // ===== stage (per wave, no block barrier) =====
    if (xint) {
        // V: 80 groups for this wave (8 rows x 10 float4-groups)
        #pragma unroll
        for (int h = 0; h < 2; ++h) {
            int g = lane + (h << 6);
            if (g < 80) {
                int vl = g / 10, c4 = (g - vl * 10) * 4;
                int v  = (wid << 3) + vl;         // tile row 0..31
                int yv = y0 + v;
                const float* bp = tc + (x0 - 4 + c4);
                float4 V1, V2, V3;
                if (yv >= 2 && yv <= H - 3) {
                    float4 A  = *(const float4*)(bp + (yv - 2) * W);
                    float4 Bq = *(const float4*)(bp + (yv - 1) * W);
                    float4 Cq = *(const float4*)(bp + yv * W);
                    float4 E  = *(const float4*)(bp + (yv + 1) * W);
                    float4 G  = *(const float4*)(bp + (yv + 2) * W);
                    float4 s04 = f4_add(A, G), s13 = f4_add(Bq, E);
                    float4 d40 = f4_sub(G, A), d31 = f4_sub(E, Bq);
                    V1 = make_float4(fmaf(6.f, Cq.x, fmaf(4.f, s13.x, s04.x)),
                                     fmaf(6.f, Cq.y, fmaf(4.f, s13.y, s04.y)),
                                     fmaf(6.f, Cq.z, fmaf(4.f, s13.z, s04.z)),
                                     fmaf(6.f, Cq.w, fmaf(4.f, s13.w, s04.w)));
                    V3 = make_float4(fmaf(-2.f, Cq.x, s04.x), fmaf(-2.f, Cq.y, s04.y),
                                     fmaf(-2.f, Cq.z, s04.z), fmaf(-2.f, Cq.w, s04.w));
                    V2 = make_float4(fmaf(2.f, d31.x, d40.x), fmaf(2.f, d31.y, d40.y),
                                     fmaf(2.f, d31.z, d40.z), fmaf(2.f, d31.w, d40.w));
                } else {
                    int um = max(yv - 1, 0), up = min(yv + 1, H - 1);
                    int ia = max(um - 1, 0), ig = min(up + 1, H - 1);
                    float4 A  = *(const float4*)(bp + ia * W);
                    float4 Bq = *(const float4*)(bp + um * W);
                    float4 Cq = *(const float4*)(bp + (um + 1) * W);
                    float4 Dq = *(const float4*)(bp + yv * W);
                    float4 E  = *(const float4*)(bp + up * W);
                    float4 F  = *(const float4*)(bp + (up - 1) * W);
                    float4 G  = *(const float4*)(bp + ig * W);
                    float4 Bm = f4_sm(A, Bq, Cq), Bc = f4_sm(Bq, Dq, E), Bp_ = f4_sm(F, E, G);
                    float4 Dm = f4_sub(Cq, A),   Dc = f4_sub(E, Bq),    Dp  = f4_sub(G, F);
                    V1 = f4_sm(Bm, Bc, Bp_); V2 = f4_sm(Dm, Dc, Dp); V3 = f4_sub(Dp, Dm);
                }
                float* d1 = &V1_s[v * VST + c4];
                float* d2 = &V2_s[v * VST + c4];
                float* d3 = &V3_s[v * VST + c4];
                d1[0] = V1.x; d1[1] = V1.y; d1[2] = V1.z; d1[3] = V1.w;
                d2[0] = V2.x; d2[1] = V2.y; d2[2] = V2.z; d2[3] = V2.w;
                d3[0] = V3.x; d3[1] = V3.y; d3[2] = V3.z; d3[3] = V3.w;
            }
        }
        // e: 100 groups for this wave (e_s rows 8*wid .. 8*wid+9)
        #pragma unroll
        for (int h = 0; h < 2; ++h) {
            int g = lane + (h << 6);
            if (g < 100) {
                int el = g / 10, c4 = (g - el * 10) * 4;
                int ve = (wid << 3) + el;
                int gy = y0 + ve - 1; gy = gy < 0 ? -gy : (gy >= H ? 2 * H - 2 - gy : gy);
                float4 p = *(const float4*)(pc + gy * W + (x0 - 4 + c4));
                float* d = &e_s[ve * VST + c4];
                d[0] = __expf(0.1f * p.x); d[1] = __expf(0.1f * p.y);
                d[2] = __expf(0.1f * p.z); d[3] = __expf(0.1f * p.w);
            }
        }
    } else {
        // x-border: scalar, clamped cols (verified path), this wave's rows only
        for (int i = lane; i < 8 * 40; i += 64) {
            int vl = i / 40, u = i - vl * 40;
            int v  = (wid << 3) + vl;
            int yv = y0 + v;
            int gx = min(max(x0 + u - 4, 0), W - 1);
            const float* bp = tc + gx;
            int um = max(yv - 1, 0), up = min(yv + 1, H - 1);
            int ia = max(um - 1, 0), ig = min(up + 1, H - 1);
            float A = bp[ia * W], Bq = bp[um * W], Cq = bp[(um + 1) * W];
            float Dq = bp[yv * W], E = bp[up * W], F = bp[(up - 1) * W], G = bp[ig * W];
            float Bm = fmaf(2.f, Bq, A) + Cq, Bc = fmaf(2.f, Dq, Bq) + E, Bp_ = fmaf(2.f, E, F) + G;
            float Dm = Cq - A, Dc = E - Bq, Dp = G - F;
            V1_s[v * VST + u] = fmaf(2.f, Bc, Bm) + Bp_;
            V2_s[v * VST + u] = fmaf(2.f, Dc, Dm) + Dp;
            V3_s[v * VST + u] = Dp - Dm;
        }
        for (int i = lane; i < 10 * 40; i += 64) {
            int el = i / 40, u = i - el * 40;
            int ve = (wid << 3) + el;
            int gy = y0 + ve - 1; gy = gy < 0 ? -gy : (gy >= H ? 2 * H - 2 - gy : gy);
            int gx = x0 + u - 4;  gx = gx < 0 ? -gx : (gx >= W ? 2 * W - 2 - gx : gx);
            e_s[ve * VST + u] = __expf(0.1f * pc[gy * W + gx]);
        }
    }

    // Same wave produces and consumes: LDS is in-order within a wave (R5-validated).
    __builtin_amdgcn_wave_barrier();
    asm volatile("" ::: "memory");

    // ===== compute: H-pass + tail (identical to R9) =====
    float V1[8], V2[8], V3[8];
    {
        const int rb = r * VST + cs + 2;   // u = cs+2+jj <-> gx = x0+cs-2+jj
        #pragma unroll
        for (int jj = 0; jj < 8; ++jj) {
            V1[jj] = V1_s[rb + jj];
            V2[jj] = V2_s[rb + jj];
            V3[jj] = V3_s[rb + jj];
        }
    }

    float xx4[4], xy4[4], yy4[4];
    #pragma unroll
    for (int j = 0; j < 4; ++j) {
        int x = x0 + cs + j;
        float xx, xy, yy;
        if (xint || (x >= 2 && x <= W - 3)) {
            xx = (V1[j] + V1[j + 4]) - 2.f * V1[j + 2];
            xy = (V2[j + 4] - V2[j]) + 2.f * (V2[j + 3] - V2[j + 1]);
            yy = (V3[j] + V3[j + 4]) + 4.f * (V3[j + 1] + V3[j + 3]) + 6.f * V3[j + 2];
        } else {
            float hdd[5], hds[5], hss[5];
            if (x == 0) {
                hdd[0]=0; hdd[1]=0;  hdd[2]=0;  hdd[3]=-1; hdd[4]=1;
                hds[0]=0; hds[1]=0;  hds[2]=-2; hds[3]=1;  hds[4]=1;
                hss[0]=0; hss[1]=0;  hss[2]=10; hss[3]=5;  hss[4]=1;
            } else if (x == 1) {
                hdd[0]=0; hdd[1]=1;  hdd[2]=-2; hdd[3]=0;  hdd[4]=1;
                hds[0]=0; hds[1]=-3; hds[2]=0;  hds[3]=2;  hds[4]=1;
                hss[0]=0; hss[1]=5;  hss[2]=6;  hss[3]=4;  hss[4]=1;
            } else if (x == W - 1) {
                hdd[0]=1; hdd[1]=-1; hdd[2]=0;  hdd[3]=0;  hdd[4]=0;
                hds[0]=-1;hds[1]=-1; hds[2]=2;  hds[3]=0;  hds[4]=0;
                hss[0]=1; hss[1]=5;  hss[2]=10; hss[3]=0;  hss[4]=0;
            } else { // x == W-2
                hdd[0]=1; hdd[1]=0;  hdd[2]=-2; hdd[3]=1;  hdd[4]=0;
                hds[0]=-1;hds[1]=-2; hds[2]=0;  hds[3]=3;  hds[4]=0;
                hss[0]=1; hss[1]=4;  hss[2]=6;  hss[3]=5;  hss[4]=0;
            }
            xx = 0.f; xy = 0.f; yy = 0.f;
            #pragma unroll
            for (int m = 0; m < 5; ++m) {
                xx = fmaf(hdd[m], V1[j + m], xx);
                xy = fmaf(hds[m], V2[j + m], xy);
                yy = fmaf(hss[m], V3[j + m], yy);
            }
        }
        xx4[j] = xx; xy4[j] = xy; yy4[j] = yy;
    }

    float m4[4] = {maskv.x, maskv.y, maskv.z, maskv.w};

    // e window 3x6: rows y-1..y+1 (e_s rows r..r+2), cols x-1..x+4 relative of cs
    float e0[6], e1[6], e2[6];
    {
        const float* eb = &e_s[r * VST + cs + 3];
        #pragma unroll
        for (int m = 0; m < 6; ++m) {
            e0[m] = eb[m];
            e1[m] = eb[VST + m];
            e2[m] = eb[2 * VST + m];
        }
    }

    float partial = 0.f;
    #pragma unroll
    for (int j = 0; j < 4; ++j) {
        if (m4[j] > 0.f) {
            const int m = j + 1;
            float xx = xx4[j], xy = xy4[j], yy = yy4[j];   // 64x scaled
            float den = xx + 6.4e-6f;                       // 64*(grad_xx+1e-7)
            float sa  = 6.4e-6f - xy;                       // 64*(1e-7-grad_xy)
            float ax = fabsf(den), ay = fabsf(yy);
            bool isH = ay < 0.41421356f * ax;    // tan(22.5), mul-compare
            bool isV = ay >= 2.41421356f * ax;   // tan(67.5)
            bool qp  = ((yy * sa) * den) > 0.f;  // sign of q
            float ec = e1[m];
            float n1 = isH ? e1[m + 1] : (isV ? e2[m] : (qp ? e2[m - 1] : e2[m + 1]));
            float n2 = isH ? e1[m - 1] : (isV ? e0[m] : (qp ? e0[m + 1] : e0[m - 1]));
            partial += __logf(__fdividef(ec, ec + n1 + n2 + 1e-7f));
        }
    }

    // ---- wave reduction + spread atomics (no block barrier anywhere) ----
    for (int off = 32; off > 0; off >>= 1)
        partial += __shfl_down(partial, off, 64);
    if (lane == 0) {
        int fid = (blockIdx.z * gridDim.y + blockIdx.y) * gridDim.x + blockIdx.x;
        if (acc_d) atomicAdd(&acc_d[(fid * 4 + wid) & (NSLOT - 1)], (double)partial);
        else       atomicAdd(acc_f, partial);
    }
}

__global__ void finalize_kernel(const double* acc_d, float* out,
                                int use_double, float inv_b)
{
    if (use_double) {
        int l = threadIdx.x;
        double s = 0.0;
        for (int i = l; i < NSLOT; i += 64) s += acc_d[i];
        for (int off = 32; off > 0; off >>= 1) s += __shfl_down(s, off, 64);
        if (l == 0) out[0] = (float)(-s * (double)inv_b);
    } else {
        if (threadIdx.x == 0) out[0] = -out[0] * inv_b;
    }
}

extern "C" void kernel_launch(void* const* d_in, const int* in_sizes, int n_in,
                              void* d_out, int out_size, void* d_ws, size_t ws_size,
                              hipStream_t stream)
{
    const float* tl = (const float*)d_in[0];
    const float* pl = (const float*)d_in[1];
    float* out = (float*)d_out;

    const int H = 512, W = 512, B = 4;

    double* acc_d = nullptr;
    float* acc_f = nullptr;
    int use_double = 0;
    if (ws_size >= NSLOT * sizeof(double)) {
        acc_d = (double*)d_ws;
        use_double = 1;
        hipMemsetAsync(acc_d, 0, NSLOT * sizeof(double), stream);
    } else {
        acc_f = out;
        hipMemsetAsync(out, 0, sizeof(float), stream);
    }

    dim3 grid(W / TILE, H / TILE, 76);
    nms_loss_kernel<<<grid, 256, 0, stream>>>(tl, pl, acc_d, acc_f, H, W);
    finalize_kernel<<<1, 64, 0, stream>>>(acc_d, out, use_double, 1.0f / (float)B);
}

// Round 13
// 58.761 us; speedup vs baseline: 1.9736x; 1.9085x over previous
//
#include <hip/hip_runtime.h>

#define BAND 16
#define NITER (BAND + 4)
#define NSLOT 1024

__global__ __launch_bounds__(256) void nms_loss_kernel(
    const float* __restrict__ tl, const float* __restrict__ pl,
    double* __restrict__ acc_d, float* __restrict__ acc_f,
    int H, int W)
{
    const int y0  = blockIdx.x * BAND;
    const int ch  = blockIdx.y;
    const float* tc = tl + (size_t)ch * H * W;
    const float* pc = pl + (size_t)ch * H * W;
    const int tid  = threadIdx.x;
    const int lane = tid & 63;
    const int c0 = tid << 1;                    // this thread's 2 output columns
    const int oa = min(max(c0 - 2, 0), W - 2);  // clamped float2 bases
    const int oc = min(c0 + 2, W - 2);
    const bool xedge = (c0 == 0) || (c0 == W - 2);

    // register rings: P (5 rows), e (3 rows), t-center/mask (3 rows), pending loads
    float P1h[5][2], P2h[5][2], P3h[5][2];
    float eh[3][4], tch[3][2];
    float t6[6], p6[6];

    // prologue: load t row y0-2 (clamp), p row y0-3 (reflect)
    {
        int tr = max(y0 - 2, 0);
        int pr = y0 - 3; pr = pr < 0 ? -pr : pr;
        const float* tb = tc + (size_t)tr * W;
        const float* pb = pc + (size_t)pr * W;
        float2 a = *(const float2*)(tb + oa), b = *(const float2*)(tb + c0), c = *(const float2*)(tb + oc);
        t6[0]=a.x; t6[1]=a.y; t6[2]=b.x; t6[3]=b.y; t6[4]=c.x; t6[5]=c.y;
        a = *(const float2*)(pb + oa); b = *(const float2*)(pb + c0); c = *(const float2*)(pb + oc);
        p6[0]=a.x; p6[1]=a.y; p6[2]=b.x; p6[3]=b.y; p6[4]=c.x; p6[5]=c.y;
    }

    float partial = 0.f;

    #pragma unroll
    for (int i = 0; i < NITER; ++i) {
        const int sP = i % 5, sE = i % 3;

        // ---- consume pending: t6 -> P(row y0-2+i) + mask; p6 -> e(row y0-3+i)
        if (!xedge) {
            float s04 = t6[0] + t6[4], s13 = t6[1] + t6[3];
            P1h[sP][0] = fmaf(-2.f, t6[2], s04);                        // hdd [1,0,-2,0,1]
            P3h[sP][0] = fmaf(6.f, t6[2], fmaf(4.f, s13, s04));          // hss [1,4,6,4,1]
            P2h[sP][0] = fmaf(2.f, t6[3] - t6[1], t6[4] - t6[0]);        // hds [-1,-2,0,2,1]
            float s04b = t6[1] + t6[5], s13b = t6[2] + t6[4];
            P1h[sP][1] = fmaf(-2.f, t6[3], s04b);
            P3h[sP][1] = fmaf(6.f, t6[3], fmaf(4.f, s13b, s04b));
            P2h[sP][1] = fmaf(2.f, t6[4] - t6[2], t6[5] - t6[1]);
        } else if (c0 == 0) {
            // colA x=0: tables over t6[0..4]; colB x=1: over t6[1..5] (verified R3 tables)
            P1h[sP][0] = t6[4] - t6[3];                                  // [0,0,0,-1,1]
            P2h[sP][0] = fmaf(-2.f, t6[2], t6[3] + t6[4]);               // [0,0,-2,1,1]
            P3h[sP][0] = fmaf(10.f, t6[2], fmaf(5.f, t6[3], t6[4]));     // [0,0,10,5,1]
            P1h[sP][1] = fmaf(-2.f, t6[3], t6[2] + t6[5]);               // [0,1,-2,0,1]
            P2h[sP][1] = fmaf(-3.f, t6[2], fmaf(2.f, t6[4], t6[5]));     // [0,-3,0,2,1]
            P3h[sP][1] = fmaf(5.f, t6[2], fmaf(6.f, t6[3], fmaf(4.f, t6[4], t6[5]))); // [0,5,6,4,1]
        } else { // c0 == W-2
            P1h[sP][0] = fmaf(-2.f, t6[2], t6[0] + t6[3]);               // [1,0,-2,1,0]
            P2h[sP][0] = fmaf(3.f, t6[3], fmaf(-2.f, t6[1], -t6[0]));    // [-1,-2,0,3,0]
            P3h[sP][0] = fmaf(5.f, t6[3], fmaf(6.f, t6[2], fmaf(4.f, t6[1], t6[0]))); // [1,4,6,5,0]
            P1h[sP][1] = t6[1] - t6[2];                                  // [1,-1,0,0,0]
            P2h[sP][1] = fmaf(2.f, t6[3], -t6[1] - t6[2]);               // [-1,-1,2,0,0]
            P3h[sP][1] = fmaf(10.f, t6[3], fmaf(5.f, t6[2], t6[1]));     // [1,5,10,0,0]
        }
        tch[sE][0] = t6[2]; tch[sE][1] = t6[3];
        eh[sE][0] = __expf(0.1f * p6[1]);   // cols c0-1..c0+2 (edge reflect = auto via clamp)
        eh[sE][1] = __expf(0.1f * p6[2]);
        eh[sE][2] = __expf(0.1f * p6[3]);
        eh[sE][3] = __expf(0.1f * p6[4]);

        // ---- issue next row loads (consumed next iteration)
        if (i + 1 < NITER) {
            int tr = y0 - 1 + i;  tr = min(max(tr, 0), H - 1);
            int pr = y0 - 2 + i;  pr = pr < 0 ? -pr : (pr >= H ? 2 * H - 2 - pr : pr);
            const float* tb = tc + (size_t)tr * W;
            const float* pb = pc + (size_t)pr * W;
            float2 a = *(const float2*)(tb + oa), b = *(const float2*)(tb + c0), c = *(const float2*)(tb + oc);
            t6[0]=a.x; t6[1]=a.y; t6[2]=b.x; t6[3]=b.y; t6[4]=c.x; t6[5]=c.y;
            a = *(const float2*)(pb + oa); b = *(const float2*)(pb + c0); c = *(const float2*)(pb + oc);
            p6[0]=a.x; p6[1]=a.y; p6[2]=b.x; p6[3]=b.y; p6[4]=c.x; p6[5]=c.y;
        }

        // ---- output row y = y0 + i - 4
        if (i >= 4) {
            const int y = y0 + i - 4;
            const int s0 = (i - 4) % 5, s1 = (i - 3) % 5, s2 = (i - 2) % 5,
                      s3 = (i - 1) % 5, s4 = i % 5;
            float xx[2], xy[2], yy[2];
            if (y >= 2 && y <= H - 3) {
                #pragma unroll
                for (int j = 0; j < 2; ++j) {
                    float a04 = P1h[s0][j] + P1h[s4][j], a13 = P1h[s1][j] + P1h[s3][j];
                    xx[j] = fmaf(6.f, P1h[s2][j], fmaf(4.f, a13, a04));      // wss
                    xy[j] = fmaf(2.f, P2h[s3][j] - P2h[s1][j], P2h[s4][j] - P2h[s0][j]); // wsd
                    yy[j] = fmaf(-2.f, P3h[s2][j], P3h[s0][j] + P3h[s4][j]); // wdd
                }
            } else {
                float wss[5], wsd[5], wdd[5];
                if (y == 0) {
                    wss[0]=0; wss[1]=0; wss[2]=10; wss[3]=5;  wss[4]=1;
                    wsd[0]=0; wsd[1]=0; wsd[2]=-4; wsd[3]=3;  wsd[4]=1;
                    wdd[0]=0; wdd[1]=0; wdd[2]=0;  wdd[3]=-1; wdd[4]=1;
                } else if (y == 1) {
                    wss[0]=0; wss[1]=5; wss[2]=6;  wss[3]=4;  wss[4]=1;
                    wsd[0]=0; wsd[1]=-3;wsd[2]=0;  wsd[3]=2;  wsd[4]=1;
                    wdd[0]=0; wdd[1]=1; wdd[2]=-2; wdd[3]=0;  wdd[4]=1;
                } else if (y == H - 1) {
                    wss[0]=1; wss[1]=5; wss[2]=10; wss[3]=0;  wss[4]=0;
                    wsd[0]=-1;wsd[1]=-3;wsd[2]=4;  wsd[3]=0;  wsd[4]=0;
                    wdd[0]=1; wdd[1]=-1;wdd[2]=0;  wdd[3]=0;  wdd[4]=0;
                } else { // y == H-2
                    wss[0]=1; wss[1]=4; wss[2]=6;  wss[3]=5;  wss[4]=0;
                    wsd[0]=-1;wsd[1]=-2;wsd[2]=0;  wsd[3]=3;  wsd[4]=0;
                    wdd[0]=1; wdd[1]=0; wdd[2]=-2; wdd[3]=1;  wdd[4]=0;
                }
                const int ss[5] = {s0, s1, s2, s3, s4};
                #pragma unroll
                for (int j = 0; j < 2; ++j) {
                    float X = 0.f, Y = 0.f, Z = 0.f;
                    #pragma unroll
                    for (int k = 0; k < 5; ++k) {
                        X = fmaf(wss[k], P1h[ss[k]][j], X);
                        Y = fmaf(wsd[k], P2h[ss[k]][j], Y);
                        Z = fmaf(wdd[k], P3h[ss[k]][j], Z);
                    }
                    xx[j] = X; xy[j] = Y; yy[j] = Z;
                }
            }

            const int et = (i - 2) % 3, em = (i - 1) % 3, eb = i % 3; // rows y-1, y, y+1
            #pragma unroll
            for (int j = 0; j < 2; ++j) {
                if (tch[et][j] > 0.f) {          // mask row y (ring slot (i-2)%3)
                    float den = xx[j] + 6.4e-6f;  // 64*(grad_xx+1e-7)
                    float sa  = 6.4e-6f - xy[j];  // 64*(1e-7-grad_xy)
                    float ax = fabsf(den), ay = fabsf(yy[j]);
                    bool isH = ay < 0.41421356f * ax;    // tan(22.5)
                    bool isV = ay >= 2.41421356f * ax;   // tan(67.5)
                    bool qp  = ((yy[j] * sa) * den) > 0.f;
                    float ec = eh[em][j + 1];
                    float n1 = isH ? eh[em][j + 2] : (isV ? eh[eb][j + 1] : (qp ? eh[eb][j] : eh[eb][j + 2]));
                    float n2 = isH ? eh[em][j]     : (isV ? eh[et][j + 1] : (qp ? eh[et][j + 2] : eh[et][j]));
                    partial += __logf(__fdividef(ec, ec + n1 + n2 + 1e-7f));
                }
            }
        }
    }

    // ---- wave reduction + spread atomics (no barriers anywhere) ----
    for (int off = 32; off > 0; off >>= 1)
        partial += __shfl_down(partial, off, 64);
    if (lane == 0) {
        int fid = (blockIdx.y * gridDim.x + blockIdx.x) * 4 + (tid >> 6);
        if (acc_d) atomicAdd(&acc_d[fid & (NSLOT - 1)], (double)partial);
        else       atomicAdd(acc_f, partial);
    }
}

__global__ void finalize_kernel(const double* acc_d, float* out,
                                int use_double, float inv_b)
{
    if (use_double) {
        int l = threadIdx.x;
        double s = 0.0;
        for (int i = l; i < NSLOT; i += 64) s += acc_d[i];
        for (int off = 32; off > 0; off >>= 1) s += __shfl_down(s, off, 64);
        if (l == 0) out[0] = (float)(-s * (double)inv_b);
    } else {
        if (threadIdx.x == 0) out[0] = -out[0] * inv_b;
    }
}

extern "C" void kernel_launch(void* const* d_in, const int* in_sizes, int n_in,
                              void* d_out, int out_size, void* d_ws, size_t ws_size,
                              hipStream_t stream)
{
    const float* tl = (const float*)d_in[0];
    const float* pl = (const float*)d_in[1];
    float* out = (float*)d_out;

    const int H = 512, W = 512, B = 4;

    double* acc_d = nullptr;
    float* acc_f = nullptr;
    int use_double = 0;
    if (ws_size >= NSLOT * sizeof(double)) {
        acc_d = (double*)d_ws;
        use_double = 1;
        hipMemsetAsync(acc_d, 0, NSLOT * sizeof(double), stream);
    } else {
        acc_f = out;
        hipMemsetAsync(out, 0, sizeof(float), stream);
    }

    dim3 grid(H / BAND, 76, 1);   // 32 bands x 76 channels = 2432 blocks, 512 cols/block
    nms_loss_kernel<<<grid, 256, 0, stream>>>(tl, pl, acc_d, acc_f, H, W);
    finalize_kernel<<<1, 64, 0, stream>>>(acc_d, out, use_double, 1.0f / (float)B);
}